// Round 5
// baseline (662.614 us; speedup 1.0000x reference)
//
#include <hip/hip_runtime.h>
#include <hip/hip_fp16.h>
#include <math.h>

// ---------------------------------------------------------------------------
// GAT 2-layer forward. Pipeline:
//   0) detect edge_index dtype (int32 vs int64) on-device
//   1) CSR build by target: histogram -> scan -> radix partition (trg>>6)
//      -> L2-local scatter. Partition pairs buffer overlays proj1/h1 region.
//   2) gemm1: proj1(fp16) = x @ W1^T (+ fused s_src1/s_trg1 logits, fp32)
//   3) agg1 : per-target softmax + weighted sum + ELU -> h1(fp16)   [unroll 4]
//   4) gemm2: proj2 = h1 @ W2^T (+ fused s_src2/s_trg2)
//   5) agg2 : per-target softmax-attention + bias + row-softmax -> out
// Workspace ~25 MB.
// ---------------------------------------------------------------------------

__device__ __forceinline__ float leaky02(float v){ return v > 0.f ? v : 0.2f*v; }
__device__ __forceinline__ float expc(float v){ return __expf(fminf(v, 60.f)); }

__device__ __forceinline__ int edge_at(const void* ei, int isI32, long long idx){
  if (isI32) return ((const int*)ei)[idx];
  return (int)((const long long*)ei)[idx];
}

// ---------------- edge dtype detection ----------------
__global__ void k_detect(const unsigned int* __restrict__ w, int nwords, int* __restrict__ flag){
  int gid = blockIdx.x*256 + threadIdx.x;
  int stride = gridDim.x*256;
  unsigned int v = 0;
  for (int idx = 2*gid + 1; idx < nwords; idx += 2*stride)
    v |= w[idx];
  unsigned long long b = __ballot(v != 0);
  if ((threadIdx.x & 63) == 0 && b != 0ULL) atomicOr(flag, 1);
}

// ---------------- CSR build ----------------
__global__ void k_hist(const void* __restrict__ ei, const int* __restrict__ flag,
                       int* __restrict__ counts, int E, int N){
  int e = blockIdx.x*256 + threadIdx.x;
  if (e < E){
    int t = edge_at(ei, *flag, (long long)e + E);
    t = min(max(t, 0), N-1);
    atomicAdd(&counts[t], 1);
  }
}

__global__ void k_scan1(const int* __restrict__ counts, int* __restrict__ temp,
                        int* __restrict__ partials, int n){
  __shared__ int lds[256];
  int tid = threadIdx.x;
  int base = blockIdx.x*1024 + tid*4;
  int a0 = (base+0 < n) ? counts[base+0] : 0;
  int a1 = (base+1 < n) ? counts[base+1] : 0;
  int a2 = (base+2 < n) ? counts[base+2] : 0;
  int a3 = (base+3 < n) ? counts[base+3] : 0;
  int p1 = a0+a1, p2 = p1+a2, p3 = p2+a3;
  lds[tid] = p3; __syncthreads();
  for (int s=1; s<256; s<<=1){
    int v = (tid>=s) ? lds[tid-s] : 0;
    __syncthreads();
    lds[tid] += v;
    __syncthreads();
  }
  int excl = lds[tid] - p3;
  if (base+0 < n) temp[base+0] = excl + a0;
  if (base+1 < n) temp[base+1] = excl + p1;
  if (base+2 < n) temp[base+2] = excl + p2;
  if (base+3 < n) temp[base+3] = excl + p3;
  if (tid == 255) partials[blockIdx.x] = lds[255];
}

__global__ void k_scan2(int* __restrict__ partials, int nb){
  int lane = threadIdx.x;
  int v = (lane < nb) ? partials[lane] : 0;
  int orig = v;
  for (int s=1; s<64; s<<=1){
    int u = __shfl_up(v, s);
    if (lane >= s) v += u;
  }
  if (lane < nb) partials[lane] = v - orig;
}

__global__ void k_scan3(const int* __restrict__ temp, const int* __restrict__ partials,
                        const int* __restrict__ counts, int* __restrict__ offsets,
                        int* __restrict__ cursor, int n){
  int tid = threadIdx.x;
  int base = blockIdx.x*1024 + tid*4;
  int add = partials[blockIdx.x];
  #pragma unroll
  for (int j=0; j<4; ++j){
    int i = base + j;
    if (i < n){
      int incl = temp[i] + add;
      offsets[i+1] = incl;
      cursor[i]    = incl - counts[i];
    }
  }
  if (blockIdx.x == 0 && tid == 0) offsets[0] = 0;
}

// per-bucket cursors: bucket b covers targets [b<<6, (b+1)<<6)
__global__ void k_initb(const int* __restrict__ offsets, int* __restrict__ bcur, int N, int nbk){
  int b = blockIdx.x*256 + threadIdx.x;
  if (b < nbk) bcur[b] = offsets[min(b<<6, N)];
}

// pass 1: partition (src,trg) pairs into bucket-contiguous regions (dense 8B appends)
__global__ void k_part(const void* __restrict__ ei, const int* __restrict__ flag,
                       int* __restrict__ bcur, int2* __restrict__ bkt, int E, int N){
  int e = blockIdx.x*256 + threadIdx.x;
  if (e < E){
    int f = *flag;
    int s = edge_at(ei, f, (long long)e);
    int t = edge_at(ei, f, (long long)e + E);
    s = min(max(s, 0), N-1);
    t = min(max(t, 0), N-1);
    int pos = atomicAdd(&bcur[t>>6], 1);
    bkt[pos] = make_int2(s, t);
  }
}

// pass 2: within-bucket scatter — positions land in an ~8KB L2-local region
__global__ void k_scatter2(const int2* __restrict__ bkt, int* __restrict__ cursor,
                           int* __restrict__ sorted, int E){
  int e = blockIdx.x*256 + threadIdx.x;
  if (e < E){
    int2 p = bkt[e];
    int pos = atomicAdd(&cursor[p.y], 1);
    sorted[pos] = p.x;
  }
}

// ---------------- layer 1 projection ----------------
__global__ __launch_bounds__(256) void k_gemm1(
    const float* __restrict__ x, const float* __restrict__ W,
    const float* __restrict__ a_src, const float* __restrict__ a_trg,
    __half* __restrict__ proj, float* __restrict__ s_src, float* __restrict__ s_trg, int n){
  const int PAD = 68;
  __shared__ float xsT[64*PAD];
  __shared__ float wT [64*PAD];
  int tid = threadIdx.x;
  int n0  = blockIdx.x*64;
  int tn = tid & 15, tm = tid >> 4;
  const float4* x4 = (const float4*)x;
  float acc[4][4] = {};

  for (int kh = 0; kh < 2; ++kh){
    __syncthreads();
    #pragma unroll
    for (int it=0; it<16; ++it){
      int idx = it*256 + tid;
      int c = idx >> 6, k = idx & 63;
      wT[k*PAD + c] = W[c*128 + kh*64 + k];
    }
    #pragma unroll
    for (int it=0; it<4; ++it){
      int idx = it*256 + tid;
      int r = idx >> 4, k4 = idx & 15;
      int row = n0 + r;
      float4 v = (row < n) ? x4[(size_t)row*32 + kh*16 + k4] : make_float4(0.f,0.f,0.f,0.f);
      xsT[(k4*4+0)*PAD + r] = v.x;
      xsT[(k4*4+1)*PAD + r] = v.y;
      xsT[(k4*4+2)*PAD + r] = v.z;
      xsT[(k4*4+3)*PAD + r] = v.w;
    }
    __syncthreads();

    #pragma unroll 8
    for (int k=0; k<64; ++k){
      float4 av = *(const float4*)&xsT[k*PAD + tm*4];
      float4 bv = *(const float4*)&wT [k*PAD + tn*4];
      float a_[4] = {av.x, av.y, av.z, av.w};
      float b_[4] = {bv.x, bv.y, bv.z, bv.w};
      #pragma unroll
      for (int i=0;i<4;++i)
        #pragma unroll
        for (int j=0;j<4;++j)
          acc[i][j] += a_[i]*b_[j];
    }
  }

  float as[4], at[4];
  #pragma unroll
  for (int j=0;j<4;++j){ as[j] = a_src[tn*4+j]; at[j] = a_trg[tn*4+j]; }
  #pragma unroll
  for (int i=0;i<4;++i){
    int row = n0 + tm*4 + i;
    float ps = 0.f, pt = 0.f;
    #pragma unroll
    for (int j=0;j<4;++j){ ps += acc[i][j]*as[j]; pt += acc[i][j]*at[j]; }
    ps += __shfl_xor(ps, 1);
    pt += __shfl_xor(pt, 1);
    if (row < n){
      __half* pr = proj + (size_t)row*64 + tn*4;
      #pragma unroll
      for (int j=0;j<4;++j) pr[j] = __float2half(acc[i][j]);
      if ((tn & 1) == 0){
        s_src[row*8 + (tn>>1)] = ps;
        s_trg[row*8 + (tn>>1)] = pt;
      }
    }
  }
}

// ---------------- layer 1 aggregation: one wave per target ----------------
__global__ __launch_bounds__(64) void k_agg1(
    const int* __restrict__ off, const int* __restrict__ srcs,
    const float* __restrict__ ss, const float* __restrict__ st,
    const __half* __restrict__ proj, const float* __restrict__ b1,
    __half* __restrict__ hout, int N){
  int t = blockIdx.x;
  int lane = threadIdx.x;
  int start = off[t], end = off[t+1];

  // pass 1: per-head exp-sum. lanes = 8 edge-groups x 8 heads (unroll 2)
  int hh = lane & 7, g = lane >> 3;
  float st1 = st[t*8 + hh];
  float part = 0.f;
  int e = start + g;
  for (; e + 8 < end; e += 16){
    int s0 = min(max(srcs[e], 0), N-1);
    int s1 = min(max(srcs[e+8], 0), N-1);
    part += expc(leaky02(ss[s0*8 + hh] + st1)) + expc(leaky02(ss[s1*8 + hh] + st1));
  }
  if (e < end){
    int s0 = min(max(srcs[e], 0), N-1);
    part += expc(leaky02(ss[s0*8 + hh] + st1));
  }
  part += __shfl_xor(part, 8);
  part += __shfl_xor(part, 16);
  part += __shfl_xor(part, 32);

  // pass 2: lane owns output component (head = lane>>3, f = lane&7); unroll 4
  int h2 = lane >> 3;
  float denom = __shfl(part, h2);
  float rd = 1.f / (denom + 1e-16f);
  float st2 = st[t*8 + h2];
  float a0 = 0.f, a1 = 0.f, a2 = 0.f, a3 = 0.f;
  e = start;
  for (; e + 4 <= end; e += 4){
    int s0 = min(max(srcs[e+0], 0), N-1);
    int s1 = min(max(srcs[e+1], 0), N-1);
    int s2 = min(max(srcs[e+2], 0), N-1);
    int s3 = min(max(srcs[e+3], 0), N-1);
    float p0 = __half2float(proj[(size_t)s0*64 + lane]);
    float p1 = __half2float(proj[(size_t)s1*64 + lane]);
    float p2 = __half2float(proj[(size_t)s2*64 + lane]);
    float p3 = __half2float(proj[(size_t)s3*64 + lane]);
    a0 += expc(leaky02(ss[s0*8 + h2] + st2)) * p0;
    a1 += expc(leaky02(ss[s1*8 + h2] + st2)) * p1;
    a2 += expc(leaky02(ss[s2*8 + h2] + st2)) * p2;
    a3 += expc(leaky02(ss[s3*8 + h2] + st2)) * p3;
  }
  for (; e < end; ++e){
    int s0 = min(max(srcs[e], 0), N-1);
    a0 += expc(leaky02(ss[s0*8 + h2] + st2)) * __half2float(proj[(size_t)s0*64 + lane]);
  }
  float z = ((a0 + a1) + (a2 + a3)) * rd + b1[lane];
  hout[(size_t)t*64 + lane] = __float2half((z > 0.f) ? z : expm1f(z));  // ELU
}

// ---------------- layer 2 projection ----------------
__global__ __launch_bounds__(256) void k_gemm2(
    const __half* __restrict__ h, const float* __restrict__ W2,
    const float* __restrict__ a_src2, const float* __restrict__ a_trg2,
    float* __restrict__ proj2, float* __restrict__ ssrc2, float* __restrict__ strg2, int n){
  __shared__ float wl[7*68];
  int tid = threadIdx.x;
  for (int i = tid; i < 7*64; i += 256){
    int f = i >> 6, k = i & 63;
    wl[f*68 + k] = W2[i];
  }
  __syncthreads();
  int f = tid & 7, ln = tid >> 3;
  int node = blockIdx.x*32 + ln;
  int fe = (f < 7) ? f : 6;
  float acc = 0.f;
  if (node < n){
    const __half* hp = h + (size_t)node*64;
    #pragma unroll
    for (int k=0; k<64; ++k)
      acc += __half2float(hp[k]) * wl[fe*68 + k];
  }
  float vs = (f < 7) ? acc * a_src2[f] : 0.f;
  float vt = (f < 7) ? acc * a_trg2[f] : 0.f;
  vs += __shfl_xor(vs,1); vt += __shfl_xor(vt,1);
  vs += __shfl_xor(vs,2); vt += __shfl_xor(vt,2);
  vs += __shfl_xor(vs,4); vt += __shfl_xor(vt,4);
  if (node < n){
    if (f < 7) proj2[(size_t)node*7 + f] = acc;
    if (f == 0){ ssrc2[node] = vs; strg2[node] = vt; }
  }
}

// ---------------- layer 2 aggregation + final softmax ----------------
__global__ __launch_bounds__(64) void k_agg2(
    const int* __restrict__ off, const int* __restrict__ srcs,
    const float* __restrict__ ss, const float* __restrict__ st,
    const float* __restrict__ proj2, const float* __restrict__ b2,
    float* __restrict__ out, int N){
  int t = blockIdx.x;
  int lane = threadIdx.x;
  int start = off[t], end = off[t+1];
  float stv = st[t];

  // pass 1: denominator (64-lane stride)
  float p = 0.f;
  for (int e = start + lane; e < end; e += 64){
    int s = min(max(srcs[e], 0), N-1);
    p += expc(leaky02(ss[s] + stv));
  }
  #pragma unroll
  for (int sdx=1; sdx<64; sdx<<=1) p += __shfl_xor(p, sdx);
  float rd = 1.f / (p + 1e-16f);

  // pass 2: 8 edge-groups x 8 feature slots (f<7 valid); unroll 2
  int f = lane & 7, g = lane >> 3;
  int fe = (f < 7) ? f : 6;
  float a0 = 0.f, a1 = 0.f;
  int e = start + g;
  for (; e + 8 < end; e += 16){
    int s0 = min(max(srcs[e], 0), N-1);
    int s1 = min(max(srcs[e+8], 0), N-1);
    a0 += expc(leaky02(ss[s0] + stv)) * proj2[(size_t)s0*7 + fe];
    a1 += expc(leaky02(ss[s1] + stv)) * proj2[(size_t)s1*7 + fe];
  }
  if (e < end){
    int s0 = min(max(srcs[e], 0), N-1);
    a0 += expc(leaky02(ss[s0] + stv)) * proj2[(size_t)s0*7 + fe];
  }
  float acc = (a0 + a1) * rd;
  acc += __shfl_xor(acc, 8);
  acc += __shfl_xor(acc, 16);
  acc += __shfl_xor(acc, 32);

  float z = (f < 7) ? acc + b2[f] : -3.0e38f;
  float m = z;
  m = fmaxf(m, __shfl_xor(m, 1));
  m = fmaxf(m, __shfl_xor(m, 2));
  m = fmaxf(m, __shfl_xor(m, 4));
  float ev = (f < 7) ? __expf(z - m) : 0.f;
  float sum = ev;
  sum += __shfl_xor(sum, 1);
  sum += __shfl_xor(sum, 2);
  sum += __shfl_xor(sum, 4);
  if (lane < 7) out[(size_t)t*7 + lane] = ev / sum;
}

// ---------------------------------------------------------------------------
extern "C" void kernel_launch(void* const* d_in, const int* in_sizes, int n_in,
                              void* d_out, int out_size, void* d_ws, size_t ws_size,
                              hipStream_t stream){
  int N = in_sizes[0] / 128;
  int E = in_sizes[1] / 2;
  const float* x   = (const float*)d_in[0];
  const void*  ei  = d_in[1];
  const float* W1  = (const float*)d_in[2];
  const float* as1 = (const float*)d_in[3];
  const float* at1 = (const float*)d_in[4];
  const float* b1  = (const float*)d_in[5];
  const float* W2  = (const float*)d_in[6];
  const float* as2 = (const float*)d_in[7];
  const float* at2 = (const float*)d_in[8];
  const float* b2  = (const float*)d_in[9];
  float* out = (float*)d_out;

  int nbk = (N + 63) >> 6;   // buckets of 64 targets

  auto aln = [](size_t v){ return (v + 255) & ~(size_t)255; };
  char* w = (char*)d_ws;
  int* flag     = (int*)w; w += aln(4);
  int* counts   = (int*)w; w += aln((size_t)N*4);
  int* temp     = (int*)w; w += aln((size_t)N*4);
  int* partials = (int*)w; w += aln(256*4);
  int* offsets  = (int*)w; w += aln((size_t)(N+1)*4);
  int* cursor   = (int*)w; w += aln((size_t)N*4);
  int* bcur     = (int*)w; w += aln((size_t)(nbk+1)*4);
  int* sorted   = (int*)w; w += aln((size_t)E*4);

  // union: bkt pairs (E*8 B) overlays [proj1, ssrc1, strg1, h1] (dead before gemm1)
  char* uni = w;
  int2*   bkt   = (int2*)uni;
  __half* proj1 = (__half*)uni;            size_t o1 = aln((size_t)N*64*2);
  float*  ssrc1 = (float*)(uni + o1);      size_t o2 = o1 + aln((size_t)N*8*4);
  float*  strg1 = (float*)(uni + o2);      size_t o3 = o2 + aln((size_t)N*8*4);
  __half* h1    = (__half*)(uni + o3);     size_t o4 = o3 + aln((size_t)N*64*2);
  size_t uniSize = (size_t)E*8 > o4 ? (size_t)E*8 : o4;
  w = uni + aln(uniSize);

  float* proj2  = (float*)w; w += aln((size_t)N*7*4 + 64);
  float* ssrc2  = (float*)w; w += aln((size_t)N*4);
  float* strg2  = (float*)w; w += aln((size_t)N*4);

  hipMemsetAsync(flag, 0, 4, stream);
  hipMemsetAsync(counts, 0, (size_t)N*4, stream);

  int eb = (E + 255) / 256;
  int nb = (N + 1023) / 1024;

  k_detect  <<<512, 256, 0, stream>>>((const unsigned int*)ei, 2*E, flag);
  k_hist    <<<eb, 256, 0, stream>>>(ei, flag, counts, E, N);
  k_scan1   <<<nb, 256, 0, stream>>>(counts, temp, partials, N);
  k_scan2   <<<1,  64,  0, stream>>>(partials, nb);
  k_scan3   <<<nb, 256, 0, stream>>>(temp, partials, counts, offsets, cursor, N);
  k_initb   <<<(nbk+255)/256, 256, 0, stream>>>(offsets, bcur, N, nbk);
  k_part    <<<eb, 256, 0, stream>>>(ei, flag, bcur, bkt, E, N);
  k_scatter2<<<eb, 256, 0, stream>>>(bkt, cursor, sorted, E);

  k_gemm1<<<(N+63)/64, 256, 0, stream>>>(x, W1, as1, at1, proj1, ssrc1, strg1, N);
  k_agg1 <<<N, 64, 0, stream>>>(offsets, sorted, ssrc1, strg1, proj1, b1, h1, N);
  k_gemm2<<<(N+31)/32, 256, 0, stream>>>(h1, W2, as2, at2, proj2, ssrc2, strg2, N);
  k_agg2 <<<N, 64, 0, stream>>>(offsets, sorted, ssrc2, strg2, proj2, b2, out, N);
}

// Round 6
// 302.630 us; speedup vs baseline: 2.1895x; 2.1895x over previous
//
#include <hip/hip_runtime.h>
#include <hip/hip_fp16.h>
#include <math.h>

// ---------------------------------------------------------------------------
// GAT 2-layer forward.
//   0) detect edge_index dtype (int32 vs int64) on-device
//   1) CSR by target: hist -> scan -> range-restricted multi-pass scatter
//      (blockIdx&7 ~ XCD id; each range's sorted-region + cursors stay in ONE
//       XCD's L2 -> full-line writebacks; trg re-reads come from L3)
//   2) gemm1: proj1(fp16) = x @ W1^T (+ fused s_src1/s_trg1 logits)
//   3) agg1f: per-target softmax + weighted sum + ELU + FUSED 64->7 layer-2
//      projection + layer-2 logits (gemm2 eliminated)
//   4) agg2 : per-target attention + bias + row-softmax -> out
// Workspace ~18.5 MB.
// ---------------------------------------------------------------------------

__device__ __forceinline__ float leaky02(float v){ return v > 0.f ? v : 0.2f*v; }
__device__ __forceinline__ float expc(float v){ return __expf(fminf(v, 60.f)); }

__device__ __forceinline__ int edge_at(const void* ei, int isI32, long long idx){
  if (isI32) return ((const int*)ei)[idx];
  return (int)((const long long*)ei)[idx];
}

// ---------------- edge dtype detection ----------------
__global__ void k_detect(const unsigned int* __restrict__ w, int nwords, int* __restrict__ flag){
  int gid = blockIdx.x*256 + threadIdx.x;
  int stride = gridDim.x*256;
  unsigned int v = 0;
  for (int idx = 2*gid + 1; idx < nwords; idx += 2*stride)
    v |= w[idx];
  unsigned long long b = __ballot(v != 0);
  if ((threadIdx.x & 63) == 0 && b != 0ULL) atomicOr(flag, 1);
}

// ---------------- CSR build ----------------
__global__ void k_hist(const void* __restrict__ ei, const int* __restrict__ flag,
                       int* __restrict__ counts, int E, int N){
  int e = blockIdx.x*256 + threadIdx.x;
  if (e < E){
    int t = edge_at(ei, *flag, (long long)e + E);
    t = min(max(t, 0), N-1);
    atomicAdd(&counts[t], 1);
  }
}

__global__ void k_scan1(const int* __restrict__ counts, int* __restrict__ temp,
                        int* __restrict__ partials, int n){
  __shared__ int lds[256];
  int tid = threadIdx.x;
  int base = blockIdx.x*1024 + tid*4;
  int a0 = (base+0 < n) ? counts[base+0] : 0;
  int a1 = (base+1 < n) ? counts[base+1] : 0;
  int a2 = (base+2 < n) ? counts[base+2] : 0;
  int a3 = (base+3 < n) ? counts[base+3] : 0;
  int p1 = a0+a1, p2 = p1+a2, p3 = p2+a3;
  lds[tid] = p3; __syncthreads();
  for (int s=1; s<256; s<<=1){
    int v = (tid>=s) ? lds[tid-s] : 0;
    __syncthreads();
    lds[tid] += v;
    __syncthreads();
  }
  int excl = lds[tid] - p3;
  if (base+0 < n) temp[base+0] = excl + a0;
  if (base+1 < n) temp[base+1] = excl + p1;
  if (base+2 < n) temp[base+2] = excl + p2;
  if (base+3 < n) temp[base+3] = excl + p3;
  if (tid == 255) partials[blockIdx.x] = lds[255];
}

__global__ void k_scan2(int* __restrict__ partials, int nb){
  int lane = threadIdx.x;
  int v = (lane < nb) ? partials[lane] : 0;
  int orig = v;
  for (int s=1; s<64; s<<=1){
    int u = __shfl_up(v, s);
    if (lane >= s) v += u;
  }
  if (lane < nb) partials[lane] = v - orig;
}

__global__ void k_scan3(const int* __restrict__ temp, const int* __restrict__ partials,
                        const int* __restrict__ counts, int* __restrict__ offsets,
                        int* __restrict__ cursor, int n){
  int tid = threadIdx.x;
  int base = blockIdx.x*1024 + tid*4;
  int add = partials[blockIdx.x];
  #pragma unroll
  for (int j=0; j<4; ++j){
    int i = base + j;
    if (i < n){
      int incl = temp[i] + add;
      offsets[i+1] = incl;
      cursor[i]    = incl - counts[i];
    }
  }
  if (blockIdx.x == 0 && tid == 0) offsets[0] = 0;
}

// range-restricted scatter: blockIdx&7 selects a target-range (~XCD-local);
// each chunk of edges is scanned once per range (trg re-reads hit L3).
__global__ void k_scatter_mp(const void* __restrict__ ei, const int* __restrict__ flag,
                             int* __restrict__ cursor, int* __restrict__ sorted,
                             int E, int N, int nch){
  int r  = blockIdx.x & 7;
  int c  = blockIdx.x >> 3;
  int per = (E + nch - 1) / nch;
  int lo = (int)((long long)E * c / nch);         // balanced chunking
  int hi = (int)((long long)E * (c+1) / nch);
  (void)per;
  int rngw = (N + 7) >> 3;
  int tlo = r * rngw, thi = min(tlo + rngw, N);
  int f = *flag;
  for (int e = lo + threadIdx.x; e < hi; e += 256){
    int t = edge_at(ei, f, (long long)e + E);
    t = min(max(t, 0), N-1);
    if (t < tlo || t >= thi) continue;
    int s = edge_at(ei, f, (long long)e);
    s = min(max(s, 0), N-1);
    int pos = atomicAdd(&cursor[t], 1);
    sorted[pos] = s;
  }
}

// ---------------- layer 1 projection ----------------
__global__ __launch_bounds__(256) void k_gemm1(
    const float* __restrict__ x, const float* __restrict__ W,
    const float* __restrict__ a_src, const float* __restrict__ a_trg,
    __half* __restrict__ proj, float* __restrict__ s_src, float* __restrict__ s_trg, int n){
  const int PAD = 68;
  __shared__ float xsT[64*PAD];
  __shared__ float wT [64*PAD];
  int tid = threadIdx.x;
  int n0  = blockIdx.x*64;
  int tn = tid & 15, tm = tid >> 4;
  const float4* x4 = (const float4*)x;
  float acc[4][4] = {};

  for (int kh = 0; kh < 2; ++kh){
    __syncthreads();
    #pragma unroll
    for (int it=0; it<16; ++it){
      int idx = it*256 + tid;
      int c = idx >> 6, k = idx & 63;
      wT[k*PAD + c] = W[c*128 + kh*64 + k];
    }
    #pragma unroll
    for (int it=0; it<4; ++it){
      int idx = it*256 + tid;
      int r = idx >> 4, k4 = idx & 15;
      int row = n0 + r;
      float4 v = (row < n) ? x4[(size_t)row*32 + kh*16 + k4] : make_float4(0.f,0.f,0.f,0.f);
      xsT[(k4*4+0)*PAD + r] = v.x;
      xsT[(k4*4+1)*PAD + r] = v.y;
      xsT[(k4*4+2)*PAD + r] = v.z;
      xsT[(k4*4+3)*PAD + r] = v.w;
    }
    __syncthreads();

    #pragma unroll 8
    for (int k=0; k<64; ++k){
      float4 av = *(const float4*)&xsT[k*PAD + tm*4];
      float4 bv = *(const float4*)&wT [k*PAD + tn*4];
      float a_[4] = {av.x, av.y, av.z, av.w};
      float b_[4] = {bv.x, bv.y, bv.z, bv.w};
      #pragma unroll
      for (int i=0;i<4;++i)
        #pragma unroll
        for (int j=0;j<4;++j)
          acc[i][j] += a_[i]*b_[j];
    }
  }

  float as[4], at[4];
  #pragma unroll
  for (int j=0;j<4;++j){ as[j] = a_src[tn*4+j]; at[j] = a_trg[tn*4+j]; }
  #pragma unroll
  for (int i=0;i<4;++i){
    int row = n0 + tm*4 + i;
    float ps = 0.f, pt = 0.f;
    #pragma unroll
    for (int j=0;j<4;++j){ ps += acc[i][j]*as[j]; pt += acc[i][j]*at[j]; }
    ps += __shfl_xor(ps, 1);
    pt += __shfl_xor(pt, 1);
    if (row < n){
      __half* pr = proj + (size_t)row*64 + tn*4;
      #pragma unroll
      for (int j=0;j<4;++j) pr[j] = __float2half(acc[i][j]);
      if ((tn & 1) == 0){
        s_src[row*8 + (tn>>1)] = ps;
        s_trg[row*8 + (tn>>1)] = pt;
      }
    }
  }
}

// ---------------- layer 1 aggregation + fused layer-2 projection ----------------
__global__ __launch_bounds__(64) void k_agg1f(
    const int* __restrict__ off, const int* __restrict__ srcs,
    const float* __restrict__ ss, const float* __restrict__ st,
    const __half* __restrict__ proj, const float* __restrict__ b1,
    const float* __restrict__ W2, const float* __restrict__ as2, const float* __restrict__ at2,
    float* __restrict__ proj2, float* __restrict__ ssrc2, float* __restrict__ strg2, int N){
  int t = blockIdx.x;
  int lane = threadIdx.x;
  int start = off[t], end = off[t+1];

  // pass 1: per-head exp-sum (8 edge-groups x 8 heads, unroll 2)
  int hh = lane & 7, g = lane >> 3;
  float st1 = st[t*8 + hh];
  float part = 0.f;
  int e = start + g;
  for (; e + 8 < end; e += 16){
    int s0 = min(max(srcs[e], 0), N-1);
    int s1 = min(max(srcs[e+8], 0), N-1);
    part += expc(leaky02(ss[s0*8 + hh] + st1)) + expc(leaky02(ss[s1*8 + hh] + st1));
  }
  if (e < end){
    int s0 = min(max(srcs[e], 0), N-1);
    part += expc(leaky02(ss[s0*8 + hh] + st1));
  }
  part += __shfl_xor(part, 8);
  part += __shfl_xor(part, 16);
  part += __shfl_xor(part, 32);

  // pass 2: lane owns component (head = lane>>3, f = lane&7); unroll 4
  int h2 = lane >> 3;
  float denom = __shfl(part, h2);
  float rd = 1.f / (denom + 1e-16f);
  float st2 = st[t*8 + h2];
  float a0 = 0.f, a1 = 0.f, a2 = 0.f, a3 = 0.f;
  e = start;
  for (; e + 4 <= end; e += 4){
    int s0 = min(max(srcs[e+0], 0), N-1);
    int s1 = min(max(srcs[e+1], 0), N-1);
    int s2 = min(max(srcs[e+2], 0), N-1);
    int s3 = min(max(srcs[e+3], 0), N-1);
    float p0 = __half2float(proj[(size_t)s0*64 + lane]);
    float p1 = __half2float(proj[(size_t)s1*64 + lane]);
    float p2 = __half2float(proj[(size_t)s2*64 + lane]);
    float p3 = __half2float(proj[(size_t)s3*64 + lane]);
    a0 += expc(leaky02(ss[s0*8 + h2] + st2)) * p0;
    a1 += expc(leaky02(ss[s1*8 + h2] + st2)) * p1;
    a2 += expc(leaky02(ss[s2*8 + h2] + st2)) * p2;
    a3 += expc(leaky02(ss[s3*8 + h2] + st2)) * p3;
  }
  for (; e < end; ++e){
    int s0 = min(max(srcs[e], 0), N-1);
    a0 += expc(leaky02(ss[s0*8 + h2] + st2)) * __half2float(proj[(size_t)s0*64 + lane]);
  }
  float z = ((a0 + a1) + (a2 + a3)) * rd + b1[lane];
  z = (z > 0.f) ? z : expm1f(z);   // ELU -> h1 row, one component per lane

  // fused layer-2 projection: proj2[t][f] = sum_c h1[c]*W2[f*64+c], + logits
  float pf[7];
  #pragma unroll
  for (int f = 0; f < 7; ++f){
    float v = z * W2[f*64 + lane];
    v += __shfl_xor(v, 1);
    v += __shfl_xor(v, 2);
    v += __shfl_xor(v, 4);
    v += __shfl_xor(v, 8);
    v += __shfl_xor(v, 16);
    v += __shfl_xor(v, 32);
    pf[f] = v;
  }
  if (lane == 0){
    float vs = 0.f, vt = 0.f;
    #pragma unroll
    for (int f = 0; f < 7; ++f){
      proj2[(size_t)t*8 + f] = pf[f];
      vs += pf[f] * as2[f];
      vt += pf[f] * at2[f];
    }
    proj2[(size_t)t*8 + 7] = 0.f;   // pad (read by agg2's lane f==7)
    ssrc2[t] = vs;
    strg2[t] = vt;
  }
}

// ---------------- layer 2 aggregation + final softmax ----------------
__global__ __launch_bounds__(64) void k_agg2(
    const int* __restrict__ off, const int* __restrict__ srcs,
    const float* __restrict__ ss, const float* __restrict__ st,
    const float* __restrict__ proj2, const float* __restrict__ b2,
    float* __restrict__ out, int N){
  int t = blockIdx.x;
  int lane = threadIdx.x;
  int start = off[t], end = off[t+1];
  float stv = st[t];

  // pass 1: denominator
  float p = 0.f;
  for (int e = start + lane; e < end; e += 64){
    int s = min(max(srcs[e], 0), N-1);
    p += expc(leaky02(ss[s] + stv));
  }
  #pragma unroll
  for (int sdx=1; sdx<64; sdx<<=1) p += __shfl_xor(p, sdx);
  float rd = 1.f / (p + 1e-16f);

  // pass 2: 8 edge-groups x 8 feature slots (f<7 valid); unroll 2
  int f = lane & 7, g = lane >> 3;
  float a0 = 0.f, a1 = 0.f;
  int e = start + g;
  for (; e + 8 < end; e += 16){
    int s0 = min(max(srcs[e], 0), N-1);
    int s1 = min(max(srcs[e+8], 0), N-1);
    a0 += expc(leaky02(ss[s0] + stv)) * proj2[(size_t)s0*8 + f];
    a1 += expc(leaky02(ss[s1] + stv)) * proj2[(size_t)s1*8 + f];
  }
  if (e < end){
    int s0 = min(max(srcs[e], 0), N-1);
    a0 += expc(leaky02(ss[s0] + stv)) * proj2[(size_t)s0*8 + f];
  }
  float acc = (a0 + a1) * rd;
  acc += __shfl_xor(acc, 8);
  acc += __shfl_xor(acc, 16);
  acc += __shfl_xor(acc, 32);

  float z = (f < 7) ? acc + b2[f] : -3.0e38f;
  float m = z;
  m = fmaxf(m, __shfl_xor(m, 1));
  m = fmaxf(m, __shfl_xor(m, 2));
  m = fmaxf(m, __shfl_xor(m, 4));
  float ev = (f < 7) ? __expf(z - m) : 0.f;
  float sum = ev;
  sum += __shfl_xor(sum, 1);
  sum += __shfl_xor(sum, 2);
  sum += __shfl_xor(sum, 4);
  if (lane < 7) out[(size_t)t*7 + lane] = ev / sum;
}

// ---------------------------------------------------------------------------
extern "C" void kernel_launch(void* const* d_in, const int* in_sizes, int n_in,
                              void* d_out, int out_size, void* d_ws, size_t ws_size,
                              hipStream_t stream){
  int N = in_sizes[0] / 128;
  int E = in_sizes[1] / 2;
  const float* x   = (const float*)d_in[0];
  const void*  ei  = d_in[1];
  const float* W1  = (const float*)d_in[2];
  const float* as1 = (const float*)d_in[3];
  const float* at1 = (const float*)d_in[4];
  const float* b1  = (const float*)d_in[5];
  const float* W2  = (const float*)d_in[6];
  const float* as2 = (const float*)d_in[7];
  const float* at2 = (const float*)d_in[8];
  const float* b2  = (const float*)d_in[9];
  float* out = (float*)d_out;

  auto aln = [](size_t v){ return (v + 255) & ~(size_t)255; };
  char* w = (char*)d_ws;
  int* flag     = (int*)w; w += aln(4);
  int* counts   = (int*)w; w += aln((size_t)N*4);
  int* temp     = (int*)w; w += aln((size_t)N*4);
  int* partials = (int*)w; w += aln(256*4);
  int* offsets  = (int*)w; w += aln((size_t)(N+1)*4);
  int* cursor   = (int*)w; w += aln((size_t)N*4);
  int* sorted   = (int*)w; w += aln((size_t)E*4);
  __half* proj1 = (__half*)w; w += aln((size_t)N*64*2);
  float* ssrc1  = (float*)w; w += aln((size_t)N*8*4);
  float* strg1  = (float*)w; w += aln((size_t)N*8*4);
  float* proj2  = (float*)w; w += aln((size_t)N*8*4);
  float* ssrc2  = (float*)w; w += aln((size_t)N*4);
  float* strg2  = (float*)w; w += aln((size_t)N*4);

  hipMemsetAsync(flag, 0, 4, stream);
  hipMemsetAsync(counts, 0, (size_t)N*4, stream);

  int eb = (E + 255) / 256;
  int nb = (N + 1023) / 1024;
  int nch = 512;                       // scatter chunks; grid = nch*8

  k_detect    <<<512, 256, 0, stream>>>((const unsigned int*)ei, 2*E, flag);
  k_hist      <<<eb, 256, 0, stream>>>(ei, flag, counts, E, N);
  k_scan1     <<<nb, 256, 0, stream>>>(counts, temp, partials, N);
  k_scan2     <<<1,  64,  0, stream>>>(partials, nb);
  k_scan3     <<<nb, 256, 0, stream>>>(temp, partials, counts, offsets, cursor, N);
  k_scatter_mp<<<nch*8, 256, 0, stream>>>(ei, flag, cursor, sorted, E, N, nch);

  k_gemm1<<<(N+63)/64, 256, 0, stream>>>(x, W1, as1, at1, proj1, ssrc1, strg1, N);
  k_agg1f<<<N, 64, 0, stream>>>(offsets, sorted, ssrc1, strg1, proj1, b1,
                                W2, as2, at2, proj2, ssrc2, strg2, N);
  k_agg2 <<<N, 64, 0, stream>>>(offsets, sorted, ssrc2, strg2, proj2, b2, out, N);
}